// Round 3
// baseline (337.997 us; speedup 1.0000x reference)
//
#include <hip/hip_runtime.h>

typedef _Float16 half8 __attribute__((ext_vector_type(8)));
typedef float f32x4 __attribute__((ext_vector_type(4)));

#define SEQ   4096
#define DIN   512
#define HID   1024
#define KMEM  256
#define NB    8
#define KC    768        // KMEM + DIN
#define VP    4352       // padded length of each phase copy of reversed u
#define OUT_H_ELEMS 33554432ull   // 8*4096*1024

__device__ __forceinline__ void load_lds16(const void* g, void* l) {
  __builtin_amdgcn_global_load_lds(
      (const __attribute__((address_space(1))) unsigned int*)g,
      (__attribute__((address_space(3))) unsigned int*)l, 16, 0, 0);
}

// ---------------- u = relu(x . W_u + b); emit xh (fp16) and v2 ----------------
// (unchanged)
__global__ __launch_bounds__(256) void u_kernel(
    const float* __restrict__ x, const float* __restrict__ Wu,
    const float* __restrict__ Wub,
    const float* __restrict__ Hf, const float* __restrict__ Wf,
    _Float16* __restrict__ xh, _Float16* __restrict__ v2,
    _Float16* __restrict__ Hh, _Float16* __restrict__ Wh)
{
  int tid_g = blockIdx.x * 256 + threadIdx.x;      // 0..2097151
  if (tid_g < KMEM * SEQ) Hh[tid_g] = (_Float16)Hf[tid_g];
  if (tid_g < HID * KC)   Wh[tid_g] = (_Float16)Wf[tid_g];
  if (tid_g < NB * 8 * 256) {                      // v2 pad zero
    int b2 = tid_g >> 11, rem = tid_g & 2047, p = rem >> 8, z = rem & 255;
    int t = (z < p) ? z : 4096 + z;                // [0,p) U [4096+p, 4352)
    v2[((size_t)b2 * 8 + p) * VP + t] = (_Float16)0.f;
  }

  int w = threadIdx.x >> 6, lane = threadIdx.x & 63;
  int row = blockIdx.x * 4 + w;               // 0..32767  (= b*4096 + s)
  const float4* xr = (const float4*)(x + (size_t)row * DIN);
  const float4* wr = (const float4*)Wu;
  float4 a0 = xr[lane * 2], a1 = xr[lane * 2 + 1];
  float4 w0 = wr[lane * 2], w1 = wr[lane * 2 + 1];
  float dot = a0.x * w0.x + a0.y * w0.y + a0.z * w0.z + a0.w * w0.w
            + a1.x * w1.x + a1.y * w1.y + a1.z * w1.z + a1.w * w1.w;
  half8 hv;
  hv[0] = (_Float16)a0.x; hv[1] = (_Float16)a0.y;
  hv[2] = (_Float16)a0.z; hv[3] = (_Float16)a0.w;
  hv[4] = (_Float16)a1.x; hv[5] = (_Float16)a1.y;
  hv[6] = (_Float16)a1.z; hv[7] = (_Float16)a1.w;
  *((half8*)(xh + (size_t)row * DIN + lane * 8)) = hv;
  #pragma unroll
  for (int off = 32; off > 0; off >>= 1) dot += __shfl_xor(dot, off);
  float u = dot + Wub[0];
  u = u > 0.f ? u : 0.f;
  if (lane < 8) {
    int s = row & (SEQ - 1), b = row >> 12;
    v2[(size_t)b * 8 * VP + (size_t)lane * VP + (4095 - s + lane)] = (_Float16)u;
  }
}

// ---------------- conv: m[b,s,k] = sum_{r=0..s} u[b,s-r] * H[k,r] ----------------
// (unchanged from round 2 — it won)
__global__ __launch_bounds__(256, 3) void conv_kernel(
    const _Float16* __restrict__ Hh, const _Float16* __restrict__ v2,
    _Float16* __restrict__ mh)
{
  __shared__ _Float16 Bs[2][128 * 64];  // [col][r-chunk 64], swizzled slots
  __shared__ _Float16 Aw[2][8 * 208];   // 8 phase copies of the u-window
  int g = blockIdx.x;                   // 0..511
  int cb = g & 15;
  int b = cb >> 1, kt = cb & 1;
  int jj = g >> 4;                      // 0..31
  int its = (jj < 16) ? jj : (47 - jj); // complement pairing: g vs g+256
  int s0 = its * 128, k0 = kt * 128;
  int tid = threadIdx.x;
  int w = tid >> 6, lane = tid & 63;
  int wr = w >> 1, wc = w & 1;
  int lm = lane & 15, q = lane >> 4;
  const _Float16* v2b = v2 + (size_t)b * 8 * VP;
  int gb = 3968 - s0;                   // window start at r0=0 (>=0, 8-aligned)

  int aoffs[4];
  #pragma unroll
  for (int mi = 0; mi < 4; mi++) {
    int X = wr * 64 + mi * 16 + lm;     // s-offset within tile (0..127)
    int p = (X + 1) & 7;
    aoffs[mi] = p * 208 + (127 - X + p) + q * 8;
  }
  int boffs[4];
  #pragma unroll
  for (int ni = 0; ni < 4; ni++) {
    int col = wc * 64 + ni * 16 + lm;
    boffs[ni] = col * 64 + ((q ^ (lm & 7)) << 3);
  }

  int ap = tid / 26, aidx = tid - ap * 26;   // A staging map (208 x 16B chunks)

  f32x4 acc[4][4] = {};
  int iters = 2 * (its + 1);            // K64 chunks to cover r in [0, s0+128)

  // preload iter 0 into buf 0
  {
    if (tid < 208)
      load_lds16(v2b + (size_t)ap * VP + gb + aidx * 8, Aw[0] + tid * 8);
    #pragma unroll
    for (int p2 = 0; p2 < 4; p2++) {
      int c = p2 * 256 + tid;
      int col = c >> 3, sl = c & 7;
      load_lds16(Hh + (size_t)(k0 + col) * SEQ + ((sl ^ (col & 7)) << 3),
                 Bs[0] + (size_t)c * 8);
    }
  }

  for (int it = 0; it < iters; ++it) {
    int buf = it & 1;
    __syncthreads();                    // vmcnt(0): buf's loads landed
    if (it + 1 < iters) {               // prefetch next K64 chunk into buf^1
      int r0 = (it + 1) * 64;
      if (tid < 208)
        load_lds16(v2b + (size_t)ap * VP + gb + r0 + aidx * 8, Aw[buf ^ 1] + tid * 8);
      #pragma unroll
      for (int p2 = 0; p2 < 4; p2++) {
        int c = p2 * 256 + tid;
        int col = c >> 3, sl = c & 7;
        load_lds16(Hh + (size_t)(k0 + col) * SEQ + r0 + ((sl ^ (col & 7)) << 3),
                   Bs[buf ^ 1] + (size_t)c * 8);
      }
    }
    #pragma unroll
    for (int kq = 0; kq < 2; kq++) {
      half8 af[4], bf[4];
      #pragma unroll
      for (int mi = 0; mi < 4; mi++)
        af[mi] = *((const half8*)(Aw[buf] + aoffs[mi] + kq * 32));
      #pragma unroll
      for (int ni = 0; ni < 4; ni++)
        bf[ni] = *((const half8*)(Bs[buf] + (boffs[ni] ^ (kq << 5))));
      #pragma unroll
      for (int mi = 0; mi < 4; mi++)
        #pragma unroll
        for (int ni = 0; ni < 4; ni++)
          acc[mi][ni] = __builtin_amdgcn_mfma_f32_16x16x32_f16(af[mi], bf[ni], acc[mi][ni], 0, 0, 0);
    }
  }
  size_t rowbase = (size_t)b * SEQ;
  #pragma unroll
  for (int mi = 0; mi < 4; mi++) {
    #pragma unroll
    for (int ni = 0; ni < 4; ni++) {
      int kout = k0 + wc * 64 + ni * 16 + lm;
      #pragma unroll
      for (int r = 0; r < 4; r++) {
        int sout = s0 + wr * 64 + mi * 16 + q * 4 + r;
        mh[(rowbase + sout) * KMEM + kout] = (_Float16)acc[mi][ni][r];
      }
    }
  }
}

// ---------------- h = relu([m, x] . W_h^T + b); also h[:, -1, :] tail ----------------
// NEW: 256x256 tile, 8 waves of 128x64 (12 ds_read per 32 MFMA, was 16 ->
// LDS floor 23us < MFMA floor 24.8us). BK=32, TRIPLE-buffered (96KB LDS,
// 1 block/CU): while computing tile t (buf t%3), stage t+2 into buf (t+2)%3,
// whose reads finished before barrier E_{t-1} -> provably race-free with ONE
// raw barrier + counted vmcnt(4) per K-tile (T4: no full drains until tail).
// setprio(1) around the 32-MFMA cluster (T5). Accumulation order identical to
// the previous h (K ascending, 32 wide) -> bit-identical results.
__global__ __launch_bounds__(512, 2) void h_kernel(
    const _Float16* __restrict__ mh, const _Float16* __restrict__ xh,
    const _Float16* __restrict__ Wh, const float* __restrict__ Whb,
    float* __restrict__ out)
{
  __shared__ _Float16 A3[3][256 * 32];   // [row][32 K], 64B rows: frag reads
  __shared__ _Float16 B3[3][256 * 32];   // naturally conflict-free (8/bank)

  int id = blockIdx.x;                   // 0..511; HW round-robins id%8 -> XCD
  int wgid = (id & 7) * 64 + (id >> 3);  // bijective (512 = 8*64)
  int mt = wgid >> 2, nt = wgid & 3;     // XCD x owns mt in [16x, 16x+16)

  int tid = threadIdx.x;
  int w = tid >> 6, lane = tid & 63;
  int wr = w >> 2, wc = w & 3;           // 2(M) x 4(N) waves, 128x64 each
  int lm = lane & 15, q = lane >> 4;

  // staging maps: chunk c = r*512+tid -> row = c>>2, slot = c&3 (linear both sides)
  int offM[2], offX[2], offB[2], ldsc[2];
  #pragma unroll
  for (int r = 0; r < 2; ++r) {
    int row = r * 128 + (tid >> 2);
    int sl = tid & 3;
    offM[r] = (mt * 256 + row) * KMEM + sl * 8;
    offX[r] = (mt * 256 + row) * DIN  + sl * 8;
    offB[r] = (nt * 256 + row) * KC   + sl * 8;
    ldsc[r] = (r * 512 + tid) * 8;
  }

#define H_STAGE(t) do {                                                        \
    const int kk_ = (t) * 32;                                                  \
    _Float16* As_ = A3[(t) % 3];                                               \
    _Float16* Bs_ = B3[(t) % 3];                                               \
    _Pragma("unroll")                                                          \
    for (int r_ = 0; r_ < 2; ++r_) {                                           \
      const _Float16* sa_ = (kk_ < KMEM) ? (mh + offM[r_] + kk_)               \
                                         : (xh + offX[r_] + (kk_ - KMEM));     \
      load_lds16(sa_, As_ + ldsc[r_]);                                         \
      load_lds16(Wh + offB[r_] + kk_, Bs_ + ldsc[r_]);                         \
    }                                                                          \
  } while (0)

  f32x4 acc[8][4] = {};

  // prologue: stage tiles 0,1; wait tile 0 landed (keep tile 1 in flight)
  H_STAGE(0); H_STAGE(1);
  asm volatile("s_waitcnt vmcnt(4)" ::: "memory");
  __builtin_amdgcn_s_barrier();
  asm volatile("" ::: "memory");

  #pragma unroll
  for (int t = 0; t < 24; ++t) {         // 24 K-tiles of 32
    if (t + 2 < 24) H_STAGE(t + 2);      // -> buf (t+2)%3, free since E_{t-1}
    const _Float16* la = A3[t % 3];
    const _Float16* lb = B3[t % 3];
    half8 af[8], bf[4];
    #pragma unroll
    for (int mi = 0; mi < 8; ++mi)
      af[mi] = *((const half8*)(la + (wr * 128 + mi * 16 + lm) * 32 + q * 8));
    #pragma unroll
    for (int ni = 0; ni < 4; ++ni)
      bf[ni] = *((const half8*)(lb + (wc * 64 + ni * 16 + lm) * 32 + q * 8));
    __builtin_amdgcn_s_setprio(1);
    #pragma unroll
    for (int mi = 0; mi < 8; ++mi)
      #pragma unroll
      for (int ni = 0; ni < 4; ++ni)
        acc[mi][ni] = __builtin_amdgcn_mfma_f32_16x16x32_f16(af[mi], bf[ni], acc[mi][ni], 0, 0, 0);
    __builtin_amdgcn_s_setprio(0);
    asm volatile("" ::: "memory");
    // guarantee tile t+1's staging landed before any wave crosses the barrier;
    // keep the newest stage-group (4 loads) in flight — never drain to 0 mid-loop
    if (t < 22)       asm volatile("s_waitcnt vmcnt(4)" ::: "memory");
    else if (t == 22) asm volatile("s_waitcnt vmcnt(0)" ::: "memory");
    if (t < 23) {
      __builtin_amdgcn_s_barrier();
      asm volatile("" ::: "memory");
    }
  }
#undef H_STAGE

  // epilogue: bias + relu + store fp32 (+ last-timestep tail)
  #pragma unroll
  for (int ni = 0; ni < 4; ++ni) {
    int colg = nt * 256 + wc * 64 + ni * 16 + lm;
    float bias = Whb[colg];
    #pragma unroll
    for (int mi = 0; mi < 8; ++mi) {
      #pragma unroll
      for (int r = 0; r < 4; ++r) {
        int rowg = mt * 256 + wr * 128 + mi * 16 + q * 4 + r;
        float v = acc[mi][ni][r] + bias;
        v = v > 0.f ? v : 0.f;
        out[(size_t)rowg * HID + colg] = v;
        if ((rowg & (SEQ - 1)) == SEQ - 1)
          out[OUT_H_ELEMS + (size_t)(rowg >> 12) * HID + colg] = v;
      }
    }
  }
}

extern "C" void kernel_launch(void* const* d_in, const int* in_sizes, int n_in,
                              void* d_out, int out_size, void* d_ws, size_t ws_size,
                              hipStream_t stream) {
  const float* x   = (const float*)d_in[0];   // (8, 4096, 512)
  const float* Wu  = (const float*)d_in[1];   // (1, 512)
  const float* Wub = (const float*)d_in[2];   // (1,)
  const float* Whw = (const float*)d_in[3];   // (1024, 768)
  const float* Whb = (const float*)d_in[4];   // (1024,)
  const float* Hf  = (const float*)d_in[5];   // (256, 4096)
  float* out = (float*)d_out;

  char* ws = (char*)d_ws;
  _Float16* Hh = (_Float16*)(ws);                         // 2,097,152 B
  _Float16* Wh = (_Float16*)(ws + 2097152);               // 1,572,864 B
  _Float16* v2 = (_Float16*)(ws + 3670016);               //   557,056 B
  _Float16* xh = (_Float16*)(ws + 4227072);               // 33,554,432 B
  _Float16* mh = (_Float16*)(ws + 37781504);              // 16,777,216 B  (end 54,558,720)

  u_kernel<<<dim3(8192), dim3(256), 0, stream>>>(x, Wu, Wub, Hf, Whw, xh, v2, Hh, Wh);
  conv_kernel<<<dim3(512), dim3(256), 0, stream>>>(Hh, v2, mh);
  h_kernel<<<dim3(512), dim3(512), 0, stream>>>(mh, xh, Wh, Whb, out);
}

// Round 4
// 308.256 us; speedup vs baseline: 1.0965x; 1.0965x over previous
//
#include <hip/hip_runtime.h>

typedef _Float16 half8 __attribute__((ext_vector_type(8)));
typedef float f32x4 __attribute__((ext_vector_type(4)));

#define SEQ   4096
#define DIN   512
#define HID   1024
#define KMEM  256
#define NB    8
#define KC    768        // KMEM + DIN
#define VP    4352       // padded length of each phase copy of reversed u
#define OUT_H_ELEMS 33554432ull   // 8*4096*1024

__device__ __forceinline__ void load_lds16(const void* g, void* l) {
  __builtin_amdgcn_global_load_lds(
      (const __attribute__((address_space(1))) unsigned int*)g,
      (__attribute__((address_space(3))) unsigned int*)l, 16, 0, 0);
}

// ---------------- u = relu(x . W_u + b); emit xh (fp16) and v2 ----------------
// (unchanged)
__global__ __launch_bounds__(256) void u_kernel(
    const float* __restrict__ x, const float* __restrict__ Wu,
    const float* __restrict__ Wub,
    const float* __restrict__ Hf, const float* __restrict__ Wf,
    _Float16* __restrict__ xh, _Float16* __restrict__ v2,
    _Float16* __restrict__ Hh, _Float16* __restrict__ Wh)
{
  int tid_g = blockIdx.x * 256 + threadIdx.x;      // 0..2097151
  if (tid_g < KMEM * SEQ) Hh[tid_g] = (_Float16)Hf[tid_g];
  if (tid_g < HID * KC)   Wh[tid_g] = (_Float16)Wf[tid_g];
  if (tid_g < NB * 8 * 256) {                      // v2 pad zero
    int b2 = tid_g >> 11, rem = tid_g & 2047, p = rem >> 8, z = rem & 255;
    int t = (z < p) ? z : 4096 + z;                // [0,p) U [4096+p, 4352)
    v2[((size_t)b2 * 8 + p) * VP + t] = (_Float16)0.f;
  }

  int w = threadIdx.x >> 6, lane = threadIdx.x & 63;
  int row = blockIdx.x * 4 + w;               // 0..32767  (= b*4096 + s)
  const float4* xr = (const float4*)(x + (size_t)row * DIN);
  const float4* wr = (const float4*)Wu;
  float4 a0 = xr[lane * 2], a1 = xr[lane * 2 + 1];
  float4 w0 = wr[lane * 2], w1 = wr[lane * 2 + 1];
  float dot = a0.x * w0.x + a0.y * w0.y + a0.z * w0.z + a0.w * w0.w
            + a1.x * w1.x + a1.y * w1.y + a1.z * w1.z + a1.w * w1.w;
  half8 hv;
  hv[0] = (_Float16)a0.x; hv[1] = (_Float16)a0.y;
  hv[2] = (_Float16)a0.z; hv[3] = (_Float16)a0.w;
  hv[4] = (_Float16)a1.x; hv[5] = (_Float16)a1.y;
  hv[6] = (_Float16)a1.z; hv[7] = (_Float16)a1.w;
  *((half8*)(xh + (size_t)row * DIN + lane * 8)) = hv;
  #pragma unroll
  for (int off = 32; off > 0; off >>= 1) dot += __shfl_xor(dot, off);
  float u = dot + Wub[0];
  u = u > 0.f ? u : 0.f;
  if (lane < 8) {
    int s = row & (SEQ - 1), b = row >> 12;
    v2[(size_t)b * 8 * VP + (size_t)lane * VP + (4095 - s + lane)] = (_Float16)u;
  }
}

// ---------------- conv: m[b,s,k] = sum_{r=0..s} u[b,s-r] * H[k,r] ----------------
// (unchanged from round 2 — it won)
__global__ __launch_bounds__(256, 3) void conv_kernel(
    const _Float16* __restrict__ Hh, const _Float16* __restrict__ v2,
    _Float16* __restrict__ mh)
{
  __shared__ _Float16 Bs[2][128 * 64];  // [col][r-chunk 64], swizzled slots
  __shared__ _Float16 Aw[2][8 * 208];   // 8 phase copies of the u-window
  int g = blockIdx.x;                   // 0..511
  int cb = g & 15;
  int b = cb >> 1, kt = cb & 1;
  int jj = g >> 4;                      // 0..31
  int its = (jj < 16) ? jj : (47 - jj); // complement pairing: g vs g+256
  int s0 = its * 128, k0 = kt * 128;
  int tid = threadIdx.x;
  int w = tid >> 6, lane = tid & 63;
  int wr = w >> 1, wc = w & 1;
  int lm = lane & 15, q = lane >> 4;
  const _Float16* v2b = v2 + (size_t)b * 8 * VP;
  int gb = 3968 - s0;                   // window start at r0=0 (>=0, 8-aligned)

  int aoffs[4];
  #pragma unroll
  for (int mi = 0; mi < 4; mi++) {
    int X = wr * 64 + mi * 16 + lm;     // s-offset within tile (0..127)
    int p = (X + 1) & 7;
    aoffs[mi] = p * 208 + (127 - X + p) + q * 8;
  }
  int boffs[4];
  #pragma unroll
  for (int ni = 0; ni < 4; ni++) {
    int col = wc * 64 + ni * 16 + lm;
    boffs[ni] = col * 64 + ((q ^ (lm & 7)) << 3);
  }

  int ap = tid / 26, aidx = tid - ap * 26;   // A staging map (208 x 16B chunks)

  f32x4 acc[4][4] = {};
  int iters = 2 * (its + 1);            // K64 chunks to cover r in [0, s0+128)

  // preload iter 0 into buf 0
  {
    if (tid < 208)
      load_lds16(v2b + (size_t)ap * VP + gb + aidx * 8, Aw[0] + tid * 8);
    #pragma unroll
    for (int p2 = 0; p2 < 4; p2++) {
      int c = p2 * 256 + tid;
      int col = c >> 3, sl = c & 7;
      load_lds16(Hh + (size_t)(k0 + col) * SEQ + ((sl ^ (col & 7)) << 3),
                 Bs[0] + (size_t)c * 8);
    }
  }

  for (int it = 0; it < iters; ++it) {
    int buf = it & 1;
    __syncthreads();                    // vmcnt(0): buf's loads landed
    if (it + 1 < iters) {               // prefetch next K64 chunk into buf^1
      int r0 = (it + 1) * 64;
      if (tid < 208)
        load_lds16(v2b + (size_t)ap * VP + gb + r0 + aidx * 8, Aw[buf ^ 1] + tid * 8);
      #pragma unroll
      for (int p2 = 0; p2 < 4; p2++) {
        int c = p2 * 256 + tid;
        int col = c >> 3, sl = c & 7;
        load_lds16(Hh + (size_t)(k0 + col) * SEQ + r0 + ((sl ^ (col & 7)) << 3),
                   Bs[buf ^ 1] + (size_t)c * 8);
      }
    }
    #pragma unroll
    for (int kq = 0; kq < 2; kq++) {
      half8 af[4], bf[4];
      #pragma unroll
      for (int mi = 0; mi < 4; mi++)
        af[mi] = *((const half8*)(Aw[buf] + aoffs[mi] + kq * 32));
      #pragma unroll
      for (int ni = 0; ni < 4; ni++)
        bf[ni] = *((const half8*)(Bs[buf] + (boffs[ni] ^ (kq << 5))));
      #pragma unroll
      for (int mi = 0; mi < 4; mi++)
        #pragma unroll
        for (int ni = 0; ni < 4; ni++)
          acc[mi][ni] = __builtin_amdgcn_mfma_f32_16x16x32_f16(af[mi], bf[ni], acc[mi][ni], 0, 0, 0);
    }
  }
  size_t rowbase = (size_t)b * SEQ;
  #pragma unroll
  for (int mi = 0; mi < 4; mi++) {
    #pragma unroll
    for (int ni = 0; ni < 4; ni++) {
      int kout = k0 + wc * 64 + ni * 16 + lm;
      #pragma unroll
      for (int r = 0; r < 4; r++) {
        int sout = s0 + wr * 64 + mi * 16 + q * 4 + r;
        mh[(rowbase + sout) * KMEM + kout] = (_Float16)acc[mi][ni][r];
      }
    }
  }
}

// ---------------- h = relu([m, x] . W_h^T + b); also h[:, -1, :] tail ----------------
// Reverted to the proven 128x128 version (two 256^2 restructures both lost on
// occupancy: <3 waves/SIMD exposes barrier latency with 1 block/CU).
// NEW: nontemporal stores for `out` (134MB, write-once, never GPU-re-read) —
// keeps mh/xh/Wh staging reads L2-resident instead of being evicted by the
// store stream.
__global__ __launch_bounds__(256) void h_kernel(
    const _Float16* __restrict__ mh, const _Float16* __restrict__ xh,
    const _Float16* __restrict__ Wh, const float* __restrict__ Whb,
    float* __restrict__ out)
{
  __shared__ _Float16 As[2][128 * 32];
  __shared__ _Float16 Bs[2][128 * 32];
  int id = blockIdx.y * 8 + blockIdx.x;   // dispatch-linear id (x fastest)
  int xcd = id & 7;
  int j = id >> 3;
  int mt = (j >> 3) * 8 + xcd;            // 0..255: mt-groups pinned per XCD
  int nt = j & 7;
  int tid = threadIdx.x, w = tid >> 6, lane = tid & 63;
  int wr = w >> 1, wc = w & 1, lm = lane & 15, q = lane >> 4;

  f32x4 acc[4][4] = {};
  // preload iter 0 into buf 0
  {
    #pragma unroll
    for (int p2 = 0; p2 < 2; p2++) {
      int c = p2 * 256 + tid;
      int row = c >> 2, ch = c & 3;
      size_t rg = (size_t)mt * 128 + row;
      load_lds16(mh + rg * KMEM + ch * 8, As[0] + (size_t)c * 8);
      load_lds16(Wh + (size_t)(nt * 128 + row) * KC + ch * 8, Bs[0] + (size_t)c * 8);
    }
  }
  for (int it = 0; it < 24; ++it) {
    int buf = it & 1;
    __syncthreads();
    if (it + 1 < 24) {
      int kk = (it + 1) * 32;
      #pragma unroll
      for (int p2 = 0; p2 < 2; p2++) {
        int c = p2 * 256 + tid;
        int row = c >> 2, ch = c & 3;
        size_t rg = (size_t)mt * 128 + row;
        const _Float16* srcA = (kk < KMEM)
            ? (mh + rg * KMEM + kk + ch * 8)
            : (xh + rg * DIN + (kk - KMEM) + ch * 8);
        load_lds16(srcA, As[buf ^ 1] + (size_t)c * 8);
        load_lds16(Wh + (size_t)(nt * 128 + row) * KC + kk + ch * 8,
                   Bs[buf ^ 1] + (size_t)c * 8);
      }
    }
    half8 af[4], bf[4];
    #pragma unroll
    for (int mi = 0; mi < 4; mi++)
      af[mi] = *((const half8*)(As[buf] + (wr * 64 + mi * 16 + lm) * 32 + q * 8));
    #pragma unroll
    for (int ni = 0; ni < 4; ni++)
      bf[ni] = *((const half8*)(Bs[buf] + (wc * 64 + ni * 16 + lm) * 32 + q * 8));
    #pragma unroll
    for (int mi = 0; mi < 4; mi++)
      #pragma unroll
      for (int ni = 0; ni < 4; ni++)
        acc[mi][ni] = __builtin_amdgcn_mfma_f32_16x16x32_f16(af[mi], bf[ni], acc[mi][ni], 0, 0, 0);
  }
  // epilogue: bias + relu + nontemporal store fp32 (+ last-timestep tail)
  #pragma unroll
  for (int ni = 0; ni < 4; ni++) {
    int colg = nt * 128 + wc * 64 + ni * 16 + lm;
    float bias = Whb[colg];
    #pragma unroll
    for (int mi = 0; mi < 4; mi++) {
      #pragma unroll
      for (int r = 0; r < 4; r++) {
        int rowg = mt * 128 + wr * 64 + mi * 16 + q * 4 + r;
        float v = acc[mi][ni][r] + bias;
        v = v > 0.f ? v : 0.f;
        __builtin_nontemporal_store(v, &out[(size_t)rowg * HID + colg]);
        if ((rowg & (SEQ - 1)) == SEQ - 1)
          __builtin_nontemporal_store(
              v, &out[OUT_H_ELEMS + (size_t)(rowg >> 12) * HID + colg]);
      }
    }
  }
}

extern "C" void kernel_launch(void* const* d_in, const int* in_sizes, int n_in,
                              void* d_out, int out_size, void* d_ws, size_t ws_size,
                              hipStream_t stream) {
  const float* x   = (const float*)d_in[0];   // (8, 4096, 512)
  const float* Wu  = (const float*)d_in[1];   // (1, 512)
  const float* Wub = (const float*)d_in[2];   // (1,)
  const float* Whw = (const float*)d_in[3];   // (1024, 768)
  const float* Whb = (const float*)d_in[4];   // (1024,)
  const float* Hf  = (const float*)d_in[5];   // (256, 4096)
  float* out = (float*)d_out;

  char* ws = (char*)d_ws;
  _Float16* Hh = (_Float16*)(ws);                         // 2,097,152 B
  _Float16* Wh = (_Float16*)(ws + 2097152);               // 1,572,864 B
  _Float16* v2 = (_Float16*)(ws + 3670016);               //   557,056 B
  _Float16* xh = (_Float16*)(ws + 4227072);               // 33,554,432 B
  _Float16* mh = (_Float16*)(ws + 37781504);              // 16,777,216 B  (end 54,558,720)

  u_kernel<<<dim3(8192), dim3(256), 0, stream>>>(x, Wu, Wub, Hf, Whw, xh, v2, Hh, Wh);
  conv_kernel<<<dim3(512), dim3(256), 0, stream>>>(Hh, v2, mh);
  h_kernel<<<dim3(8, 256), dim3(256), 0, stream>>>(mh, xh, Wh, Whb, out);
}